// Round 7
// baseline (2092.393 us; speedup 1.0000x reference)
//
#include <hip/hip_runtime.h>
#include <cfloat>

#define B_  8
#define N_  2048
#define H_  256
#define L_  4
#define K_  16
#define G_  512
#define M0_ 256
#define M1_ 128
#define C_  128
#define BN_ 16384   // B_*N_
#define KP_ 768     // packed split-bf16 K (3*H_)

typedef unsigned short ushort_t;
typedef __attribute__((ext_vector_type(8))) short short8;
typedef __attribute__((ext_vector_type(4))) float f32x4;

// ---------------- workspace layout (bytes) ----------------
#define OFF_H     ((size_t)0)            // 16 MB  h (fp32, persistent)
#define OFF_APACK ((size_t)16777216)     // 25.2 MB  P-pack [hi,lo,hi] (Q read via seg remap)
#define OFF_SQ    ((size_t)67108864)     // 64 KB
#define OFF_IDX   ((size_t)67174400)     // 1 MB
#define OFF_STATS ((size_t)68222976)     // 4 KB (512 doubles)
#define OFF_SCSH  ((size_t)68227072)     // 2 KB
#define OFF_BCAT  ((size_t)68229120)     // 2 KB
#define OFF_P0    ((size_t)68231168)     // 16 KB
#define OFF_P1    ((size_t)68247552)
#define OFF_P2    ((size_t)68255744)
#define OFF_D     ((size_t)69206016)     // 134.2 MB dmat; overlays below (stream-ordered safe)
#define OFF_T     (OFF_D + (size_t)0)           // 16 MB (alive gather_max -> bn2; dmat dead)
#define OFF_UV    (OFF_D + (size_t)50331648)    // 33.5 MB (alive uv gemm -> gather); also y
#define OFF_QW    (OFF_D + (size_t)83886080)    // 0.79 MB weight packs
#define OFF_PMAX  (OFF_D + (size_t)84672512)    // 256 KB
#define WS_NEEDED ((size_t)203423744)

// ---------------- helpers ----------------
static __device__ __forceinline__ ushort_t f2bf(float f) {
    unsigned u = __float_as_uint(f);
    unsigned r = (u + 0x7fffu + ((u >> 16) & 1u)) >> 16;   // RNE
    return (ushort_t)r;
}
static __device__ __forceinline__ float bf2f(ushort_t h) {
    return __uint_as_float(((unsigned)h) << 16);
}
// P-pack layout per row: [hi(0:256), lo(256:512), hi(512:768)]
static __device__ __forceinline__ void pack3(float v, ushort_t* A, size_t base, int f) {
    ushort_t hi = f2bf(v);
    ushort_t lo = f2bf(v - bf2f(hi));
    A[base + f] = hi; A[base + H_ + f] = lo; A[base + 2 * H_ + f] = hi;
}

// ---------------- kernels ----------------

// h = x @ Wf + bf ; also pack h into Apack
__global__ void feat_pack(const float* __restrict__ x, const float* __restrict__ Wf,
                          const float* __restrict__ bfv, float* __restrict__ h,
                          ushort_t* __restrict__ Ap) {
    int pt = blockIdx.x;
    int f  = threadIdx.x;
    float x0 = x[pt * 3 + 0], x1 = x[pt * 3 + 1], x2 = x[pt * 3 + 2];
    float v = x0 * Wf[f] + x1 * Wf[H_ + f] + x2 * Wf[2 * H_ + f] + bfv[f];
    h[(size_t)pt * H_ + f] = v;
    pack3(v, Ap, (size_t)pt * KP_, f);
}

// W (256 x Nd) -> Qpack (Nd x 768) rows [hi,hi,lo] of W^T
__global__ void pack_wT(const float* __restrict__ W, ushort_t* __restrict__ Qp, int Nd) {
    int n = blockIdx.x, k = threadIdx.x;
    float w = W[(size_t)k * Nd + n];
    ushort_t hi = f2bf(w), lo = f2bf(w - bf2f(hi));
    size_t base = (size_t)n * KP_;
    Qp[base + k] = hi; Qp[base + H_ + k] = hi; Qp[base + 2 * H_ + k] = lo;
}

// Qcat for fused u|v gemm: rows 0..255 = (We_a - We_b)^T, rows 256..511 = We_b^T
__global__ void pack_qcat(const float* __restrict__ We_l, const float* __restrict__ be_l,
                          ushort_t* __restrict__ Qp, float* __restrict__ bcat) {
    int n = blockIdx.x, k = threadIdx.x;
    float w;
    if (n < H_) w = We_l[(size_t)k * H_ + n] - We_l[(size_t)H_ * H_ + (size_t)k * H_ + n];
    else        w = We_l[(size_t)H_ * H_ + (size_t)k * H_ + (n - H_)];
    ushort_t hi = f2bf(w), lo = f2bf(w - bf2f(hi));
    size_t base = (size_t)n * KP_;
    Qp[base + k] = hi; Qp[base + H_ + k] = hi; Qp[base + 2 * H_ + k] = lo;
    if (k == 0) bcat[n] = (n < H_) ? be_l[n] : 0.f;
}

// ---- split-bf16 MFMA GEMM: out = P (M x K) . Q^T (N x K) ----
// mode 0: out[r][c] = acc + aux[c]
// mode 2: out[r][c] = resid[r][c] + alphap[aidx]*(acc+aux[c])
__global__ __launch_bounds__(256) void mfma_gemm(
    const ushort_t* __restrict__ P, const ushort_t* __restrict__ Q,
    const float* __restrict__ aux, float* __restrict__ out,
    int Kd, int ldOut, int mode, const float* __restrict__ resid,
    const float* __restrict__ alphap, int aidx) {
    __shared__ __align__(16) ushort_t As[128 * 32];
    __shared__ __align__(16) ushort_t Bs[128 * 32];
    int i0 = blockIdx.y * 128, j0 = blockIdx.x * 128;
    int tid = threadIdx.x;
    int lane = tid & 63, wave = tid >> 6;
    int wm = wave & 1, wn = wave >> 1;
    int m16 = lane & 15, kq = (lane >> 4) * 8;

    f32x4 acc[4][4];
    f32x4 zero = {0.f, 0.f, 0.f, 0.f};
#pragma unroll
    for (int i = 0; i < 4; ++i)
#pragma unroll
        for (int j = 0; j < 4; ++j) acc[i][j] = zero;

    int srow = tid >> 2;
    int skc  = (tid & 3) * 8;

    for (int k0 = 0; k0 < Kd; k0 += 32) {
#pragma unroll
        for (int s = 0; s < 2; ++s) {
            int row = srow + s * 64;
            const ushort_t* gpA = P + (size_t)(i0 + row) * Kd + k0 + skc;
            const ushort_t* gpB = Q + (size_t)(j0 + row) * Kd + k0 + skc;
            __builtin_amdgcn_global_load_lds(
                (const __attribute__((address_space(1))) void*)gpA,
                (__attribute__((address_space(3))) void*)(As + (size_t)(wave * 64 + s * 256) * 8),
                16, 0, 0);
            __builtin_amdgcn_global_load_lds(
                (const __attribute__((address_space(1))) void*)gpB,
                (__attribute__((address_space(3))) void*)(Bs + (size_t)(wave * 64 + s * 256) * 8),
                16, 0, 0);
        }
        __syncthreads();
        short8 af[4], bfr[4];
#pragma unroll
        for (int fi = 0; fi < 4; ++fi)
            af[fi] = *(const short8*)(As + (wm * 64 + fi * 16 + m16) * 32 + kq);
#pragma unroll
        for (int fj = 0; fj < 4; ++fj)
            bfr[fj] = *(const short8*)(Bs + (wn * 64 + fj * 16 + m16) * 32 + kq);
#pragma unroll
        for (int fi = 0; fi < 4; ++fi)
#pragma unroll
            for (int fj = 0; fj < 4; ++fj)
                acc[fi][fj] = __builtin_amdgcn_mfma_f32_16x16x32_bf16(
                    af[fi], bfr[fj], acc[fi][fj], 0, 0, 0);
        __syncthreads();
    }
    float alpha = (mode == 2) ? alphap[aidx] : 0.f;
    int rbase = i0 + wm * 64 + (lane >> 4) * 4;
    int cbase = j0 + wn * 64 + m16;
#pragma unroll
    for (int fi = 0; fi < 4; ++fi) {
#pragma unroll
        for (int fj = 0; fj < 4; ++fj) {
            int c = cbase + fj * 16;
            float a = aux[c];
#pragma unroll
            for (int r = 0; r < 4; ++r) {
                int gr = rbase + fi * 16 + r;
                size_t oidx = (size_t)gr * ldOut + c;
                float val;
                if (mode == 2) val = resid[oidx] + alpha * (acc[fi][fj][r] + a);
                else           val = acc[fi][fj][r] + a;
                out[oidx] = val;
            }
        }
    }
}

// ---- symmetric gram: D[i][j] = sq[j] - 2 <x_i, x_j>, upper-tri tile pairs only ----
// 1-D grid 1088: z = blk&7 (XCD pin: one batch per XCD -> 3 MB A-set fits 4 MB L2),
// p = blk>>3 in [0,136) enumerates bi<=bj tile pairs.
// B-side reads P-pack with segment remap (0,2,1) to realize Q = [hi,hi,lo].
// Both output orientations staged through LDS for contiguous 512B NT row writes.
__global__ __launch_bounds__(256) void gram_sym(const ushort_t* __restrict__ Ap,
                                                const float* __restrict__ sqb,
                                                float* __restrict__ D) {
    __shared__ __align__(16) ushort_t As[128 * 32];
    __shared__ __align__(16) ushort_t Bs[128 * 32];
    __shared__ __align__(16) float stage[4224];   // 32x132 (normal) / 128x33 (transposed)
    int blk = blockIdx.x;
    int z = blk & 7;
    int p = blk >> 3;
    int bi = 0, rem = p;
    while (rem >= 16 - bi) { rem -= 16 - bi; ++bi; }
    int bj = bi + rem;
    const ushort_t* Pz = Ap + (size_t)z * N_ * KP_;
    const float* sqz = sqb + (size_t)z * N_;
    float* Dz = D + (size_t)z * N_ * N_;
    int i0 = bi * 128, j0 = bj * 128;

    int tid = threadIdx.x;
    int lane = tid & 63, wave = tid >> 6;
    int wm = wave & 1, wn = wave >> 1;
    int m16 = lane & 15, q4 = lane >> 4;
    int kq = q4 * 8;

    f32x4 acc[4][4];
    f32x4 zero = {0.f, 0.f, 0.f, 0.f};
#pragma unroll
    for (int i = 0; i < 4; ++i)
#pragma unroll
        for (int j = 0; j < 4; ++j) acc[i][j] = zero;

    int srow = tid >> 2;
    int skc  = (tid & 3) * 8;

    for (int k0 = 0; k0 < KP_; k0 += 32) {
        // Q segment remap: seg0->seg0(hi), seg1->seg2(hi), seg2->seg1(lo)
        int kb = (k0 < 256) ? k0 : ((k0 < 512) ? k0 + 256 : k0 - 256);
#pragma unroll
        for (int s = 0; s < 2; ++s) {
            int row = srow + s * 64;
            const ushort_t* gpA = Pz + (size_t)(i0 + row) * KP_ + k0 + skc;
            const ushort_t* gpB = Pz + (size_t)(j0 + row) * KP_ + kb + skc;
            __builtin_amdgcn_global_load_lds(
                (const __attribute__((address_space(1))) void*)gpA,
                (__attribute__((address_space(3))) void*)(As + (size_t)(wave * 64 + s * 256) * 8),
                16, 0, 0);
            __builtin_amdgcn_global_load_lds(
                (const __attribute__((address_space(1))) void*)gpB,
                (__attribute__((address_space(3))) void*)(Bs + (size_t)(wave * 64 + s * 256) * 8),
                16, 0, 0);
        }
        __syncthreads();
        short8 af[4], bfr[4];
#pragma unroll
        for (int fi = 0; fi < 4; ++fi)
            af[fi] = *(const short8*)(As + (wm * 64 + fi * 16 + m16) * 32 + kq);
#pragma unroll
        for (int fj = 0; fj < 4; ++fj)
            bfr[fj] = *(const short8*)(Bs + (wn * 64 + fj * 16 + m16) * 32 + kq);
#pragma unroll
        for (int fi = 0; fi < 4; ++fi)
#pragma unroll
            for (int fj = 0; fj < 4; ++fj)
                acc[fi][fj] = __builtin_amdgcn_mfma_f32_16x16x32_bf16(
                    af[fi], bfr[fj], acc[fi][fj], 0, 0, 0);
        __syncthreads();
    }

    float scl[4];
#pragma unroll
    for (int fj = 0; fj < 4; ++fj) scl[fj] = sqz[j0 + wn * 64 + fj * 16 + m16];
    float sr[4][4];
#pragma unroll
    for (int fi = 0; fi < 4; ++fi) {
        float4 s4 = *(const float4*)(sqz + i0 + wm * 64 + fi * 16 + q4 * 4);
        sr[fi][0] = s4.x; sr[fi][1] = s4.y; sr[fi][2] = s4.z; sr[fi][3] = s4.w;
    }

    // normal orientation: 4 chunks of 32 rows, staged [32][132]
#pragma unroll
    for (int ch = 0; ch < 4; ++ch) {
        __syncthreads();
        if (wm == (ch >> 1)) {
            int fi0 = (ch & 1) * 2;
#pragma unroll
            for (int f2 = 0; f2 < 2; ++f2)
#pragma unroll
                for (int fj = 0; fj < 4; ++fj)
#pragma unroll
                    for (int r = 0; r < 4; ++r)
                        stage[(f2 * 16 + q4 * 4 + r) * 132 + wn * 64 + fj * 16 + m16] =
                            scl[fj] - 2.f * acc[fi0 + f2][fj][r];
        }
        __syncthreads();
        int row = tid >> 3, c0 = (tid & 7) * 16;
        const float* srcp = stage + row * 132 + c0;
        float* dstp = Dz + (size_t)(i0 + ch * 32 + row) * N_ + j0 + c0;
#pragma unroll
        for (int v = 0; v < 4; ++v) {
            f32x4 o = *(const f32x4*)(srcp + 4 * v);
            __builtin_nontemporal_store(o, (f32x4*)(dstp + 4 * v));
        }
    }

    // transposed orientation (off-diagonal tiles): 4 chunks of 32 D^T rows, staged [128][33]
    if (bi != bj) {
#pragma unroll
        for (int ch = 0; ch < 4; ++ch) {
            __syncthreads();
            if (wn == (ch >> 1)) {
                int fj0 = (ch & 1) * 2;
#pragma unroll
                for (int f2 = 0; f2 < 2; ++f2) {
                    int tcl = f2 * 16 + m16;
#pragma unroll
                    for (int fi = 0; fi < 4; ++fi)
#pragma unroll
                        for (int r = 0; r < 4; ++r)
                            stage[(wm * 64 + fi * 16 + q4 * 4 + r) * 33 + tcl] =
                                sr[fi][r] - 2.f * acc[fi][fj0 + f2][r];
                }
            }
            __syncthreads();
            int drow = tid & 31;
            int seg = (tid >> 5) * 16;
            float tmp[16];
#pragma unroll
            for (int kk = 0; kk < 16; ++kk) tmp[kk] = stage[(seg + kk) * 33 + drow];
            float* dstp = Dz + (size_t)(j0 + ch * 32 + drow) * N_ + i0 + seg;
#pragma unroll
            for (int v = 0; v < 4; ++v) {
                f32x4 o = {tmp[4 * v], tmp[4 * v + 1], tmp[4 * v + 2], tmp[4 * v + 3]};
                __builtin_nontemporal_store(o, (f32x4*)(dstp + 4 * v));
            }
        }
    }
}

// ---- radix-select top-16 smallest per row (exact, lex (value,col) tie-break) ----
// wave-per-row; histogram of top byte of sortable key -> crossing bin -> direct emit
// below-bin + small-set selection within bin. Output order arbitrary (consumer is max).
__global__ __launch_bounds__(256) void topk16(const float* __restrict__ D,
                                              int* __restrict__ idxb) {
    __shared__ int hist[4][256];
    __shared__ unsigned long long cand[4][256];
    __shared__ int cnt[4], ocnt[4], binfo[4][2];
    int w = threadIdx.x >> 6, lane = threadIdx.x & 63;
    int row = blockIdx.x * 4 + w;
    const float* dp = D + (size_t)row * N_;
    unsigned sk[32];
#pragma unroll
    for (int t = 0; t < 32; ++t) {
        float v = __builtin_nontemporal_load(dp + lane + (t << 6));
        unsigned u = __float_as_uint(v);
        sk[t] = (u & 0x80000000u) ? ~u : (u | 0x80000000u);
    }
    for (int i = lane; i < 256; i += 64) hist[w][i] = 0;
    if (lane == 0) { cnt[w] = 0; ocnt[w] = 0; }
    __syncthreads();
#pragma unroll
    for (int t = 0; t < 32; ++t) atomicAdd(&hist[w][sk[t] >> 24], 1);
    __syncthreads();
    int h[4];
    int base4 = 4 * lane;
#pragma unroll
    for (int q = 0; q < 4; ++q) h[q] = hist[w][base4 + q];
    int lsum = h[0] + h[1] + h[2] + h[3];
    int pre = lsum;
#pragma unroll
    for (int off = 1; off < 64; off <<= 1) {
        int nb = __shfl_up(pre, off);
        if (lane >= off) pre += nb;
    }
    int e = pre - lsum;   // exclusive prefix at this lane's first bin
#pragma unroll
    for (int q = 0; q < 4; ++q) {
        if (e < 16 && e + h[q] >= 16) { binfo[w][0] = base4 + q; binfo[w][1] = e; }
        e += h[q];
    }
    __syncthreads();
    unsigned bs = (unsigned)binfo[w][0];
    int cnt_lt = binfo[w][1];
    int rneed = 16 - cnt_lt;
#pragma unroll
    for (int t = 0; t < 32; ++t) {
        unsigned bb = sk[t] >> 24;
        int col = lane + (t << 6);
        if (bb < bs) {
            int s = atomicAdd(&ocnt[w], 1);
            idxb[row * 16 + s] = col;
        } else if (bb == bs) {
            int s = atomicAdd(&cnt[w], 1);
            if (s < 256) cand[w][s] = ((unsigned long long)sk[t] << 32) | (unsigned)col;
        }
    }
    __syncthreads();
    int cn = cnt[w];
    if (cn <= 256) {
        for (int it = 0; it < rneed; ++it) {
            unsigned long long best = ~0ull;
            for (int i = lane; i < cn; i += 64) {
                unsigned long long c = cand[w][i];
                if (c < best) best = c;
            }
#pragma unroll
            for (int off = 32; off; off >>= 1) {
                unsigned long long o = __shfl_xor(best, off);
                if (o < best) best = o;
            }
            for (int i = lane; i < cn; i += 64) {
                if (cand[w][i] == best) {
                    cand[w][i] = ~0ull;
                    int s = atomicAdd(&ocnt[w], 1);
                    idxb[row * 16 + s] = (int)(unsigned)(best & 0xffffffffu);
                }
            }
        }
    } else {
        // pathological (>256 keys share crossing byte): full serial selection, exact
        unsigned mask = 0;
        for (int it = 0; it < 16; ++it) {
            unsigned long long key = ~0ull;
#pragma unroll
            for (int t = 0; t < 32; ++t) {
                if (!((mask >> t) & 1u)) {
                    unsigned long long k2 =
                        ((unsigned long long)sk[t] << 32) | (unsigned)(lane + (t << 6));
                    if (k2 < key) key = k2;
                }
            }
#pragma unroll
            for (int off = 32; off; off >>= 1) {
                unsigned long long o = __shfl_xor(key, off);
                if (o < key) key = o;
            }
            unsigned jw = (unsigned)(key & 0xffffffffu);
            if ((unsigned)lane == (jw & 63u)) mask |= 1u << (jw >> 6);
            if (lane == 0) idxb[row * 16 + it] = (int)jw;
        }
    }
}

// t[b,i,h] = uv[row][h] + max_k uv[(b,idx_k)][256+h]
__global__ void gather_max(const float* __restrict__ uv, const int* __restrict__ idxb,
                           float* __restrict__ outp) {
    int row = blockIdx.x;
    int b = row >> 11;
    int h = threadIdx.x;
    const int* ip = idxb + row * 16;
    float m = -FLT_MAX;
#pragma unroll
    for (int k = 0; k < 16; ++k) {
        int j = ip[k];
        m = fmaxf(m, uv[((size_t)((b << 11) + j)) * 512 + 256 + h]);
    }
    outp[(size_t)row * H_ + h] = uv[(size_t)row * 512 + h] + m;
}

// ---- batchnorm over (B,N) per feature ----
__global__ void bn_zero(double* s) { s[threadIdx.x] = 0.0; }

__global__ void bn_stats(const float* __restrict__ X, double* __restrict__ sums) {
    int f = threadIdx.x;
    int r0 = blockIdx.x * 64;
    double s = 0.0, s2 = 0.0;
    for (int r = 0; r < 64; ++r) {
        float v = X[(size_t)(r0 + r) * H_ + f];
        s += v; s2 += (double)v * v;
    }
    atomicAdd(&sums[f], s);
    atomicAdd(&sums[H_ + f], s2);
}

__global__ void bn_final(const double* __restrict__ sums, const float* __restrict__ g,
                         const float* __restrict__ b, float* __restrict__ scsh) {
    int f = threadIdx.x;
    double m  = sums[f] / (double)BN_;
    double var = sums[H_ + f] / (double)BN_ - m * m;
    double inv = 1.0 / sqrt(var + 1e-5);
    float sc = g[f] * (float)inv;
    scsh[f] = sc;
    scsh[H_ + f] = b[f] - (float)m * sc;
}

// BN+ReLU fused with split-bf16 packing and (optional) row sqnorm reduce.
__global__ void bn_apply_pack(const float* __restrict__ X, const float* __restrict__ scsh,
                              ushort_t* __restrict__ Ap, float* __restrict__ sq) {
    int row = blockIdx.x, f = threadIdx.x;
    float v = X[(size_t)row * H_ + f] * scsh[f] + scsh[H_ + f];
    v = fmaxf(v, 0.f);
    pack3(v, Ap, (size_t)row * KP_, f);
    if (sq) {
        float s = v * v;
#pragma unroll
        for (int off = 32; off; off >>= 1) s += __shfl_down(s, off);
        __shared__ float red[4];
        if ((f & 63) == 0) red[f >> 6] = s;
        __syncthreads();
        if (f == 0) sq[row] = red[0] + red[1] + red[2] + red[3];
    }
}

__global__ void maxpool1(const float* __restrict__ y, float* __restrict__ pmax) {
    int b = blockIdx.x, gc = blockIdx.y, nc = blockIdx.z;
    int g = gc * 256 + threadIdx.x;
    const float* yb = y + ((size_t)b * N_ + (size_t)nc * 128) * G_;
    float m = -FLT_MAX;
    for (int n = 0; n < 128; ++n) m = fmaxf(m, yb[(size_t)n * G_ + g]);
    pmax[((size_t)(b * 16 + nc)) * G_ + g] = m;
}

__global__ void maxpool2(const float* __restrict__ pmax, float* __restrict__ p) {
    int b = blockIdx.x;
    int g = blockIdx.y * 256 + threadIdx.x;
    float m = -FLT_MAX;
    for (int c = 0; c < 16; ++c) m = fmaxf(m, pmax[((size_t)(b * 16 + c)) * G_ + g]);
    p[(size_t)b * G_ + g] = m;
}

// parallel split-K head gemm: grid(M, Nd/64), 256 thr = 64 cols x 4 k-slices
__global__ __launch_bounds__(256) void head_gemm(const float* __restrict__ A,
                                                 const float* __restrict__ W,
                                                 const float* __restrict__ bias,
                                                 float* __restrict__ Cc,
                                                 int Kd, int Nd, int relu) {
    int m = blockIdx.x;
    int c0 = blockIdx.y * 64;
    int cl = threadIdx.x & 63;
    int ks = threadIdx.x >> 6;
    int kper = Kd >> 2;
    const float* Ap = A + (size_t)m * Kd + (size_t)ks * kper;
    const float* Wp = W + (size_t)ks * kper * Nd + c0 + cl;
    float acc = 0.f;
    for (int k = 0; k < kper; k += 8) {
#pragma unroll
        for (int u2 = 0; u2 < 8; ++u2)
            acc += Ap[k + u2] * Wp[(size_t)(k + u2) * Nd];
    }
    __shared__ float red[4][64];
    red[ks][cl] = acc;
    __syncthreads();
    if (ks == 0) {
        float s = red[0][cl] + red[1][cl] + red[2][cl] + red[3][cl] + bias[c0 + cl];
        if (relu) s = fmaxf(s, 0.f);
        Cc[(size_t)m * Nd + c0 + cl] = s;
    }
}

// ---------------- launch ----------------
extern "C" void kernel_launch(void* const* d_in, const int* in_sizes, int n_in,
                              void* d_out, int out_size, void* d_ws, size_t ws_size,
                              hipStream_t stream) {
    (void)in_sizes; (void)n_in; (void)out_size;
    if (ws_size < WS_NEEDED) return;

    const float* x    = (const float*)d_in[0];
    const float* Wf   = (const float*)d_in[2];
    const float* bfv  = (const float*)d_in[3];
    const float* Wnn  = (const float*)d_in[4];
    const float* bnn  = (const float*)d_in[5];
    const float* g1   = (const float*)d_in[6];
    const float* b1   = (const float*)d_in[7];
    const float* We   = (const float*)d_in[8];
    const float* be   = (const float*)d_in[9];
    const float* g2   = (const float*)d_in[10];
    const float* b2   = (const float*)d_in[11];
    const float* Wl   = (const float*)d_in[12];
    const float* bl   = (const float*)d_in[13];
    const float* alpha= (const float*)d_in[14];
    const float* gg   = (const float*)d_in[15];
    const float* bgb  = (const float*)d_in[16];
    const float* Wg   = (const float*)d_in[17];
    const float* bg2  = (const float*)d_in[18];
    const float* Wm1  = (const float*)d_in[19];
    const float* bm1  = (const float*)d_in[20];
    const float* Wm2  = (const float*)d_in[21];
    const float* bm2  = (const float*)d_in[22];
    const float* Wm3  = (const float*)d_in[23];
    const float* bm3  = (const float*)d_in[24];
    float* outp = (float*)d_out;

    char* ws = (char*)d_ws;
    float*    h    = (float*)(ws + OFF_H);
    ushort_t* Ap   = (ushort_t*)(ws + OFF_APACK);
    float*    sqb  = (float*)(ws + OFF_SQ);
    int*      idxb = (int*)  (ws + OFF_IDX);
    double*   stats= (double*)(ws + OFF_STATS);
    float*    scsh = (float*)(ws + OFF_SCSH);
    float*    bcat = (float*)(ws + OFF_BCAT);
    float*    p0   = (float*)(ws + OFF_P0);
    float*    p1   = (float*)(ws + OFF_P1);
    float*    p2   = (float*)(ws + OFF_P2);
    float*    dmat = (float*)(ws + OFF_D);
    float*    t    = (float*)(ws + OFF_T);
    float*    uv   = (float*)(ws + OFF_UV);
    float*    y    = (float*)(ws + OFF_UV);
    ushort_t* Qw   = (ushort_t*)(ws + OFF_QW);
    float*    pmax = (float*)(ws + OFF_PMAX);

    auto bn_pre = [&](const float* src, const float* g, const float* b) {
        hipLaunchKernelGGL(bn_zero, dim3(1), dim3(512), 0, stream, stats);
        hipLaunchKernelGGL(bn_stats, dim3(256), dim3(256), 0, stream, src, stats);
        hipLaunchKernelGGL(bn_final, dim3(1), dim3(256), 0, stream, stats, g, b, scsh);
    };

    // h = x@Wf+bf (+pack), t = h@Wnn+bnn via MFMA
    hipLaunchKernelGGL(feat_pack, dim3(BN_), dim3(256), 0, stream, x, Wf, bfv, h, Ap);
    hipLaunchKernelGGL(pack_wT, dim3(H_), dim3(256), 0, stream, Wnn, Qw, H_);
    hipLaunchKernelGGL(mfma_gemm, dim3(2, 128), dim3(256), 0, stream,
                       Ap, Qw, bnn, t, KP_, H_, 0,
                       (const float*)nullptr, (const float*)nullptr, 0);

    for (int l = 0; l < L_; ++l) {
        const float* src1 = (l == 0) ? t : h;
        bn_pre(src1, g1 + l * H_, b1 + l * H_);
        hipLaunchKernelGGL(bn_apply_pack, dim3(BN_), dim3(256), 0, stream,
                           src1, scsh, Ap, sqb);
        // symmetric gram -> D (both triangles written, upper computed), XCD-pinned
        hipLaunchKernelGGL(gram_sym, dim3(1088), dim3(256), 0, stream,
                           Ap, sqb, dmat);
        hipLaunchKernelGGL(topk16, dim3(BN_ / 4), dim3(256), 0, stream, dmat, idxb);
        // fused u|v gemm (N=512)
        hipLaunchKernelGGL(pack_qcat, dim3(512), dim3(256), 0, stream,
                           We + (size_t)l * 2 * H_ * H_, be + (size_t)l * H_, Qw, bcat);
        hipLaunchKernelGGL(mfma_gemm, dim3(4, 128), dim3(256), 0, stream,
                           Ap, Qw, bcat, uv, KP_, 512, 0,
                           (const float*)nullptr, (const float*)nullptr, 0);
        hipLaunchKernelGGL(gather_max, dim3(BN_), dim3(256), 0, stream, uv, idxb, t);
        // BN2 + Wl with fused residual: h = h + alpha[l]*(xb@Wl + bl)
        bn_pre(t, g2 + l * H_, b2 + l * H_);
        hipLaunchKernelGGL(bn_apply_pack, dim3(BN_), dim3(256), 0, stream,
                           t, scsh, Ap, (float*)nullptr);
        hipLaunchKernelGGL(pack_wT, dim3(H_), dim3(256), 0, stream,
                           Wl + (size_t)l * H_ * H_, Qw, H_);
        hipLaunchKernelGGL(mfma_gemm, dim3(2, 128), dim3(256), 0, stream,
                           Ap, Qw, bl + (size_t)l * H_, h, KP_, H_, 2,
                           h, alpha, l);
    }

    // head
    bn_pre(h, gg, bgb);
    hipLaunchKernelGGL(bn_apply_pack, dim3(BN_), dim3(256), 0, stream,
                       h, scsh, Ap, (float*)nullptr);
    hipLaunchKernelGGL(pack_wT, dim3(G_), dim3(256), 0, stream, Wg, Qw, G_);
    hipLaunchKernelGGL(mfma_gemm, dim3(4, 128), dim3(256), 0, stream,
                       Ap, Qw, bg2, y, KP_, G_, 0,
                       (const float*)nullptr, (const float*)nullptr, 0);
    hipLaunchKernelGGL(maxpool1, dim3(8, 2, 16), dim3(256), 0, stream, y, pmax);
    hipLaunchKernelGGL(maxpool2, dim3(8, 2), dim3(256), 0, stream, pmax, p0);
    hipLaunchKernelGGL(head_gemm, dim3(8, 4), dim3(256), 0, stream, p0, Wm1, bm1, p1, G_, M0_, 1);
    hipLaunchKernelGGL(head_gemm, dim3(8, 2), dim3(256), 0, stream, p1, Wm2, bm2, p2, M0_, M1_, 1);
    hipLaunchKernelGGL(head_gemm, dim3(8, 2), dim3(256), 0, stream, p2, Wm3, bm3, outp, M1_, C_, 0);
}

// Round 8
// 1537.213 us; speedup vs baseline: 1.3612x; 1.3612x over previous
//
#include <hip/hip_runtime.h>
#include <cfloat>

#define B_  8
#define N_  2048
#define H_  256
#define L_  4
#define K_  16
#define G_  512
#define M0_ 256
#define M1_ 128
#define C_  128
#define BN_ 16384   // B_*N_
#define KP_ 768     // packed split-bf16 K (3*H_)

typedef unsigned short ushort_t;
typedef __attribute__((ext_vector_type(8))) short short8;
typedef __attribute__((ext_vector_type(4))) float f32x4;

// ---------------- workspace layout (bytes) ----------------
#define OFF_H     ((size_t)0)            // 16 MB  h (fp32, persistent)
#define OFF_APACK ((size_t)16777216)     // 25.2 MB  P-pack [hi,lo,hi] (Q read via seg remap)
#define OFF_SQ    ((size_t)67108864)     // 64 KB
#define OFF_IDX   ((size_t)67174400)     // 1 MB
#define OFF_STATS ((size_t)68222976)     // 4 KB (512 doubles)
#define OFF_SCSH  ((size_t)68227072)     // 2 KB
#define OFF_BCAT  ((size_t)68229120)     // 2 KB
#define OFF_P0    ((size_t)68231168)     // 16 KB
#define OFF_P1    ((size_t)68247552)
#define OFF_P2    ((size_t)68255744)
#define OFF_D     ((size_t)69206016)     // 134.2 MB dmat; overlays below (stream-ordered safe)
#define OFF_T     (OFF_D + (size_t)0)           // 16 MB (alive gather_max -> bn2; dmat dead)
#define OFF_UV    (OFF_D + (size_t)50331648)    // 33.5 MB (alive uv gemm -> gather); also y
#define OFF_QW    (OFF_D + (size_t)83886080)    // 0.79 MB weight packs
#define OFF_PMAX  (OFF_D + (size_t)84672512)    // 256 KB
#define WS_NEEDED ((size_t)203423744)

// ---------------- helpers ----------------
static __device__ __forceinline__ ushort_t f2bf(float f) {
    unsigned u = __float_as_uint(f);
    unsigned r = (u + 0x7fffu + ((u >> 16) & 1u)) >> 16;   // RNE
    return (ushort_t)r;
}
static __device__ __forceinline__ float bf2f(ushort_t h) {
    return __uint_as_float(((unsigned)h) << 16);
}
// P-pack layout per row: [hi(0:256), lo(256:512), hi(512:768)]
static __device__ __forceinline__ void pack3(float v, ushort_t* A, size_t base, int f) {
    ushort_t hi = f2bf(v);
    ushort_t lo = f2bf(v - bf2f(hi));
    A[base + f] = hi; A[base + H_ + f] = lo; A[base + 2 * H_ + f] = hi;
}

// ---------------- kernels ----------------

// h = x @ Wf + bf ; also pack h into Apack
__global__ void feat_pack(const float* __restrict__ x, const float* __restrict__ Wf,
                          const float* __restrict__ bfv, float* __restrict__ h,
                          ushort_t* __restrict__ Ap) {
    int pt = blockIdx.x;
    int f  = threadIdx.x;
    float x0 = x[pt * 3 + 0], x1 = x[pt * 3 + 1], x2 = x[pt * 3 + 2];
    float v = x0 * Wf[f] + x1 * Wf[H_ + f] + x2 * Wf[2 * H_ + f] + bfv[f];
    h[(size_t)pt * H_ + f] = v;
    pack3(v, Ap, (size_t)pt * KP_, f);
}

// W (256 x Nd) -> Qpack (Nd x 768) rows [hi,hi,lo] of W^T
__global__ void pack_wT(const float* __restrict__ W, ushort_t* __restrict__ Qp, int Nd) {
    int n = blockIdx.x, k = threadIdx.x;
    float w = W[(size_t)k * Nd + n];
    ushort_t hi = f2bf(w), lo = f2bf(w - bf2f(hi));
    size_t base = (size_t)n * KP_;
    Qp[base + k] = hi; Qp[base + H_ + k] = hi; Qp[base + 2 * H_ + k] = lo;
}

// Qcat for fused u|v gemm: rows 0..255 = (We_a - We_b)^T, rows 256..511 = We_b^T
__global__ void pack_qcat(const float* __restrict__ We_l, const float* __restrict__ be_l,
                          ushort_t* __restrict__ Qp, float* __restrict__ bcat) {
    int n = blockIdx.x, k = threadIdx.x;
    float w;
    if (n < H_) w = We_l[(size_t)k * H_ + n] - We_l[(size_t)H_ * H_ + (size_t)k * H_ + n];
    else        w = We_l[(size_t)H_ * H_ + (size_t)k * H_ + (n - H_)];
    ushort_t hi = f2bf(w), lo = f2bf(w - bf2f(hi));
    size_t base = (size_t)n * KP_;
    Qp[base + k] = hi; Qp[base + H_ + k] = hi; Qp[base + 2 * H_ + k] = lo;
    if (k == 0) bcat[n] = (n < H_) ? be_l[n] : 0.f;
}

// ---- split-bf16 MFMA GEMM: out = P (M x K) . Q^T (N x K) ----
// mode 0: out[r][c] = acc + aux[c]
// mode 2: out[r][c] = resid[r][c] + alphap[aidx]*(acc+aux[c])
__global__ __launch_bounds__(256) void mfma_gemm(
    const ushort_t* __restrict__ P, const ushort_t* __restrict__ Q,
    const float* __restrict__ aux, float* __restrict__ out,
    int Kd, int ldOut, int mode, const float* __restrict__ resid,
    const float* __restrict__ alphap, int aidx) {
    __shared__ __align__(16) ushort_t As[128 * 32];
    __shared__ __align__(16) ushort_t Bs[128 * 32];
    int i0 = blockIdx.y * 128, j0 = blockIdx.x * 128;
    int tid = threadIdx.x;
    int lane = tid & 63, wave = tid >> 6;
    int wm = wave & 1, wn = wave >> 1;
    int m16 = lane & 15, kq = (lane >> 4) * 8;

    f32x4 acc[4][4];
    f32x4 zero = {0.f, 0.f, 0.f, 0.f};
#pragma unroll
    for (int i = 0; i < 4; ++i)
#pragma unroll
        for (int j = 0; j < 4; ++j) acc[i][j] = zero;

    int srow = tid >> 2;
    int skc  = (tid & 3) * 8;

    for (int k0 = 0; k0 < Kd; k0 += 32) {
#pragma unroll
        for (int s = 0; s < 2; ++s) {
            int row = srow + s * 64;
            const ushort_t* gpA = P + (size_t)(i0 + row) * Kd + k0 + skc;
            const ushort_t* gpB = Q + (size_t)(j0 + row) * Kd + k0 + skc;
            __builtin_amdgcn_global_load_lds(
                (const __attribute__((address_space(1))) void*)gpA,
                (__attribute__((address_space(3))) void*)(As + (size_t)(wave * 64 + s * 256) * 8),
                16, 0, 0);
            __builtin_amdgcn_global_load_lds(
                (const __attribute__((address_space(1))) void*)gpB,
                (__attribute__((address_space(3))) void*)(Bs + (size_t)(wave * 64 + s * 256) * 8),
                16, 0, 0);
        }
        __syncthreads();
        short8 af[4], bfr[4];
#pragma unroll
        for (int fi = 0; fi < 4; ++fi)
            af[fi] = *(const short8*)(As + (wm * 64 + fi * 16 + m16) * 32 + kq);
#pragma unroll
        for (int fj = 0; fj < 4; ++fj)
            bfr[fj] = *(const short8*)(Bs + (wn * 64 + fj * 16 + m16) * 32 + kq);
#pragma unroll
        for (int fi = 0; fi < 4; ++fi)
#pragma unroll
            for (int fj = 0; fj < 4; ++fj)
                acc[fi][fj] = __builtin_amdgcn_mfma_f32_16x16x32_bf16(
                    af[fi], bfr[fj], acc[fi][fj], 0, 0, 0);
        __syncthreads();
    }
    float alpha = (mode == 2) ? alphap[aidx] : 0.f;
    int rbase = i0 + wm * 64 + (lane >> 4) * 4;
    int cbase = j0 + wn * 64 + m16;
#pragma unroll
    for (int fi = 0; fi < 4; ++fi) {
#pragma unroll
        for (int fj = 0; fj < 4; ++fj) {
            int c = cbase + fj * 16;
            float a = aux[c];
#pragma unroll
            for (int r = 0; r < 4; ++r) {
                int gr = rbase + fi * 16 + r;
                size_t oidx = (size_t)gr * ldOut + c;
                float val;
                if (mode == 2) val = resid[oidx] + alpha * (acc[fi][fj][r] + a);
                else           val = acc[fi][fj][r] + a;
                out[oidx] = val;
            }
        }
    }
}

// ---- symmetric gram: D[i][j] = sq[j] - 2 <x_i, x_j>, upper-tri tile pairs only ----
// 1-D grid 1088: z = blk&7 (XCD pin: one batch per XCD -> 3 MB A-set fits 4 MB L2),
// p = blk>>3 in [0,136) enumerates bi<=bj tile pairs.
// B-side reads P-pack with segment remap (0,2,1) to realize Q = [hi,hi,lo].
// Direct NT stores from registers (R6 scheme: measured 155 MB WRITE, coalesces fine).
__global__ __launch_bounds__(256) void gram_sym(const ushort_t* __restrict__ Ap,
                                                const float* __restrict__ sqb,
                                                float* __restrict__ D) {
    __shared__ __align__(16) ushort_t As[128 * 32];
    __shared__ __align__(16) ushort_t Bs[128 * 32];
    int blk = blockIdx.x;
    int z = blk & 7;
    int p = blk >> 3;
    int bi = 0, rem = p;
    while (rem >= 16 - bi) { rem -= 16 - bi; ++bi; }
    int bj = bi + rem;
    const ushort_t* Pz = Ap + (size_t)z * N_ * KP_;
    const float* sqz = sqb + (size_t)z * N_;
    float* Dz = D + (size_t)z * N_ * N_;
    int i0 = bi * 128, j0 = bj * 128;

    int tid = threadIdx.x;
    int lane = tid & 63, wave = tid >> 6;
    int wm = wave & 1, wn = wave >> 1;
    int m16 = lane & 15, q4 = lane >> 4;
    int kq = q4 * 8;

    f32x4 acc[4][4];
    f32x4 zero = {0.f, 0.f, 0.f, 0.f};
#pragma unroll
    for (int i = 0; i < 4; ++i)
#pragma unroll
        for (int j = 0; j < 4; ++j) acc[i][j] = zero;

    int srow = tid >> 2;
    int skc  = (tid & 3) * 8;

    for (int k0 = 0; k0 < KP_; k0 += 32) {
        // Q segment remap: seg0->seg0(hi), seg1->seg2(hi), seg2->seg1(lo)
        int kb = (k0 < 256) ? k0 : ((k0 < 512) ? k0 + 256 : k0 - 256);
#pragma unroll
        for (int s = 0; s < 2; ++s) {
            int row = srow + s * 64;
            const ushort_t* gpA = Pz + (size_t)(i0 + row) * KP_ + k0 + skc;
            const ushort_t* gpB = Pz + (size_t)(j0 + row) * KP_ + kb + skc;
            __builtin_amdgcn_global_load_lds(
                (const __attribute__((address_space(1))) void*)gpA,
                (__attribute__((address_space(3))) void*)(As + (size_t)(wave * 64 + s * 256) * 8),
                16, 0, 0);
            __builtin_amdgcn_global_load_lds(
                (const __attribute__((address_space(1))) void*)gpB,
                (__attribute__((address_space(3))) void*)(Bs + (size_t)(wave * 64 + s * 256) * 8),
                16, 0, 0);
        }
        __syncthreads();
        short8 af[4], bfr[4];
#pragma unroll
        for (int fi = 0; fi < 4; ++fi)
            af[fi] = *(const short8*)(As + (wm * 64 + fi * 16 + m16) * 32 + kq);
#pragma unroll
        for (int fj = 0; fj < 4; ++fj)
            bfr[fj] = *(const short8*)(Bs + (wn * 64 + fj * 16 + m16) * 32 + kq);
#pragma unroll
        for (int fi = 0; fi < 4; ++fi)
#pragma unroll
            for (int fj = 0; fj < 4; ++fj)
                acc[fi][fj] = __builtin_amdgcn_mfma_f32_16x16x32_bf16(
                    af[fi], bfr[fj], acc[fi][fj], 0, 0, 0);
        __syncthreads();
    }
    int rbase = i0 + wm * 64 + q4 * 4;
    int cbase = j0 + wn * 64 + m16;
#pragma unroll
    for (int fi = 0; fi < 4; ++fi) {
        int gr0 = rbase + fi * 16;
        float4 s4 = *(const float4*)(sqz + gr0);   // sq of this lane's 4 rows
        float sr[4] = {s4.x, s4.y, s4.z, s4.w};
#pragma unroll
        for (int fj = 0; fj < 4; ++fj) {
            int c = cbase + fj * 16;
            float sc = sqz[c];
#pragma unroll
            for (int r = 0; r < 4; ++r)
                __builtin_nontemporal_store(sc - 2.f * acc[fi][fj][r],
                                            Dz + (size_t)(gr0 + r) * N_ + c);
            if (bi != bj) {   // transposed tile: D[c][gr0..gr0+3], contiguous 16B
                f32x4 o;
                o[0] = sr[0] - 2.f * acc[fi][fj][0];
                o[1] = sr[1] - 2.f * acc[fi][fj][1];
                o[2] = sr[2] - 2.f * acc[fi][fj][2];
                o[3] = sr[3] - 2.f * acc[fi][fj][3];
                __builtin_nontemporal_store(o, (f32x4*)(Dz + (size_t)c * N_ + gr0));
            }
        }
    }
}

// ---- radix-select top-16 smallest per row (exact, lex (value,col) tie-break) ----
__global__ __launch_bounds__(256) void topk16(const float* __restrict__ D,
                                              int* __restrict__ idxb) {
    __shared__ int hist[4][256];
    __shared__ unsigned long long cand[4][256];
    __shared__ int cnt[4], ocnt[4], binfo[4][2];
    int w = threadIdx.x >> 6, lane = threadIdx.x & 63;
    int row = blockIdx.x * 4 + w;
    const float* dp = D + (size_t)row * N_;
    unsigned sk[32];
#pragma unroll
    for (int t = 0; t < 32; ++t) {
        float v = __builtin_nontemporal_load(dp + lane + (t << 6));
        unsigned u = __float_as_uint(v);
        sk[t] = (u & 0x80000000u) ? ~u : (u | 0x80000000u);
    }
    for (int i = lane; i < 256; i += 64) hist[w][i] = 0;
    if (lane == 0) { cnt[w] = 0; ocnt[w] = 0; }
    __syncthreads();
#pragma unroll
    for (int t = 0; t < 32; ++t) atomicAdd(&hist[w][sk[t] >> 24], 1);
    __syncthreads();
    int h[4];
    int base4 = 4 * lane;
#pragma unroll
    for (int q = 0; q < 4; ++q) h[q] = hist[w][base4 + q];
    int lsum = h[0] + h[1] + h[2] + h[3];
    int pre = lsum;
#pragma unroll
    for (int off = 1; off < 64; off <<= 1) {
        int nb = __shfl_up(pre, off);
        if (lane >= off) pre += nb;
    }
    int e = pre - lsum;   // exclusive prefix at this lane's first bin
#pragma unroll
    for (int q = 0; q < 4; ++q) {
        if (e < 16 && e + h[q] >= 16) { binfo[w][0] = base4 + q; binfo[w][1] = e; }
        e += h[q];
    }
    __syncthreads();
    unsigned bs = (unsigned)binfo[w][0];
    int cnt_lt = binfo[w][1];
    int rneed = 16 - cnt_lt;
#pragma unroll
    for (int t = 0; t < 32; ++t) {
        unsigned bb = sk[t] >> 24;
        int col = lane + (t << 6);
        if (bb < bs) {
            int s = atomicAdd(&ocnt[w], 1);
            idxb[row * 16 + s] = col;
        } else if (bb == bs) {
            int s = atomicAdd(&cnt[w], 1);
            if (s < 256) cand[w][s] = ((unsigned long long)sk[t] << 32) | (unsigned)col;
        }
    }
    __syncthreads();
    int cn = cnt[w];
    if (cn <= 256) {
        for (int it = 0; it < rneed; ++it) {
            unsigned long long best = ~0ull;
            for (int i = lane; i < cn; i += 64) {
                unsigned long long c = cand[w][i];
                if (c < best) best = c;
            }
#pragma unroll
            for (int off = 32; off; off >>= 1) {
                unsigned long long o = __shfl_xor(best, off);
                if (o < best) best = o;
            }
            for (int i = lane; i < cn; i += 64) {
                if (cand[w][i] == best) {
                    cand[w][i] = ~0ull;
                    int s = atomicAdd(&ocnt[w], 1);
                    idxb[row * 16 + s] = (int)(unsigned)(best & 0xffffffffu);
                }
            }
        }
    } else {
        // pathological (>256 keys share crossing byte): full serial selection, exact
        unsigned mask = 0;
        for (int it = 0; it < 16; ++it) {
            unsigned long long key = ~0ull;
#pragma unroll
            for (int t = 0; t < 32; ++t) {
                if (!((mask >> t) & 1u)) {
                    unsigned long long k2 =
                        ((unsigned long long)sk[t] << 32) | (unsigned)(lane + (t << 6));
                    if (k2 < key) key = k2;
                }
            }
#pragma unroll
            for (int off = 32; off; off >>= 1) {
                unsigned long long o = __shfl_xor(key, off);
                if (o < key) key = o;
            }
            unsigned jw = (unsigned)(key & 0xffffffffu);
            if ((unsigned)lane == (jw & 63u)) mask |= 1u << (jw >> 6);
            if (lane == 0) idxb[row * 16 + it] = (int)jw;
        }
    }
}

// t[b,i,h] = uv[row][h] + max_k uv[(b,idx_k)][256+h]
__global__ void gather_max(const float* __restrict__ uv, const int* __restrict__ idxb,
                           float* __restrict__ outp) {
    int row = blockIdx.x;
    int b = row >> 11;
    int h = threadIdx.x;
    const int* ip = idxb + row * 16;
    float m = -FLT_MAX;
#pragma unroll
    for (int k = 0; k < 16; ++k) {
        int j = ip[k];
        m = fmaxf(m, uv[((size_t)((b << 11) + j)) * 512 + 256 + h]);
    }
    outp[(size_t)row * H_ + h] = uv[(size_t)row * 512 + h] + m;
}

// ---- batchnorm over (B,N) per feature ----
__global__ void bn_zero(double* s) { s[threadIdx.x] = 0.0; }

__global__ void bn_stats(const float* __restrict__ X, double* __restrict__ sums) {
    int f = threadIdx.x;
    int r0 = blockIdx.x * 64;
    double s = 0.0, s2 = 0.0;
    for (int r = 0; r < 64; ++r) {
        float v = X[(size_t)(r0 + r) * H_ + f];
        s += v; s2 += (double)v * v;
    }
    atomicAdd(&sums[f], s);
    atomicAdd(&sums[H_ + f], s2);
}

__global__ void bn_final(const double* __restrict__ sums, const float* __restrict__ g,
                         const float* __restrict__ b, float* __restrict__ scsh) {
    int f = threadIdx.x;
    double m  = sums[f] / (double)BN_;
    double var = sums[H_ + f] / (double)BN_ - m * m;
    double inv = 1.0 / sqrt(var + 1e-5);
    float sc = g[f] * (float)inv;
    scsh[f] = sc;
    scsh[H_ + f] = b[f] - (float)m * sc;
}

// BN+ReLU fused with split-bf16 packing and (optional) row sqnorm reduce.
__global__ void bn_apply_pack(const float* __restrict__ X, const float* __restrict__ scsh,
                              ushort_t* __restrict__ Ap, float* __restrict__ sq) {
    int row = blockIdx.x, f = threadIdx.x;
    float v = X[(size_t)row * H_ + f] * scsh[f] + scsh[H_ + f];
    v = fmaxf(v, 0.f);
    pack3(v, Ap, (size_t)row * KP_, f);
    if (sq) {
        float s = v * v;
#pragma unroll
        for (int off = 32; off; off >>= 1) s += __shfl_down(s, off);
        __shared__ float red[4];
        if ((f & 63) == 0) red[f >> 6] = s;
        __syncthreads();
        if (f == 0) sq[row] = red[0] + red[1] + red[2] + red[3];
    }
}

__global__ void maxpool1(const float* __restrict__ y, float* __restrict__ pmax) {
    int b = blockIdx.x, gc = blockIdx.y, nc = blockIdx.z;
    int g = gc * 256 + threadIdx.x;
    const float* yb = y + ((size_t)b * N_ + (size_t)nc * 128) * G_;
    float m = -FLT_MAX;
    for (int n = 0; n < 128; ++n) m = fmaxf(m, yb[(size_t)n * G_ + g]);
    pmax[((size_t)(b * 16 + nc)) * G_ + g] = m;
}

__global__ void maxpool2(const float* __restrict__ pmax, float* __restrict__ p) {
    int b = blockIdx.x;
    int g = blockIdx.y * 256 + threadIdx.x;
    float m = -FLT_MAX;
    for (int c = 0; c < 16; ++c) m = fmaxf(m, pmax[((size_t)(b * 16 + c)) * G_ + g]);
    p[(size_t)b * G_ + g] = m;
}

// parallel split-K head gemm: grid(M, Nd/64), 256 thr = 64 cols x 4 k-slices
__global__ __launch_bounds__(256) void head_gemm(const float* __restrict__ A,
                                                 const float* __restrict__ W,
                                                 const float* __restrict__ bias,
                                                 float* __restrict__ Cc,
                                                 int Kd, int Nd, int relu) {
    int m = blockIdx.x;
    int c0 = blockIdx.y * 64;
    int cl = threadIdx.x & 63;
    int ks = threadIdx.x >> 6;
    int kper = Kd >> 2;
    const float* Ap = A + (size_t)m * Kd + (size_t)ks * kper;
    const float* Wp = W + (size_t)ks * kper * Nd + c0 + cl;
    float acc = 0.f;
    for (int k = 0; k < kper; k += 8) {
#pragma unroll
        for (int u2 = 0; u2 < 8; ++u2)
            acc += Ap[k + u2] * Wp[(size_t)(k + u2) * Nd];
    }
    __shared__ float red[4][64];
    red[ks][cl] = acc;
    __syncthreads();
    if (ks == 0) {
        float s = red[0][cl] + red[1][cl] + red[2][cl] + red[3][cl] + bias[c0 + cl];
        if (relu) s = fmaxf(s, 0.f);
        Cc[(size_t)m * Nd + c0 + cl] = s;
    }
}

// ---------------- launch ----------------
extern "C" void kernel_launch(void* const* d_in, const int* in_sizes, int n_in,
                              void* d_out, int out_size, void* d_ws, size_t ws_size,
                              hipStream_t stream) {
    (void)in_sizes; (void)n_in; (void)out_size;
    if (ws_size < WS_NEEDED) return;

    const float* x    = (const float*)d_in[0];
    const float* Wf   = (const float*)d_in[2];
    const float* bfv  = (const float*)d_in[3];
    const float* Wnn  = (const float*)d_in[4];
    const float* bnn  = (const float*)d_in[5];
    const float* g1   = (const float*)d_in[6];
    const float* b1   = (const float*)d_in[7];
    const float* We   = (const float*)d_in[8];
    const float* be   = (const float*)d_in[9];
    const float* g2   = (const float*)d_in[10];
    const float* b2   = (const float*)d_in[11];
    const float* Wl   = (const float*)d_in[12];
    const float* bl   = (const float*)d_in[13];
    const float* alpha= (const float*)d_in[14];
    const float* gg   = (const float*)d_in[15];
    const float* bgb  = (const float*)d_in[16];
    const float* Wg   = (const float*)d_in[17];
    const float* bg2  = (const float*)d_in[18];
    const float* Wm1  = (const float*)d_in[19];
    const float* bm1  = (const float*)d_in[20];
    const float* Wm2  = (const float*)d_in[21];
    const float* bm2  = (const float*)d_in[22];
    const float* Wm3  = (const float*)d_in[23];
    const float* bm3  = (const float*)d_in[24];
    float* outp = (float*)d_out;

    char* ws = (char*)d_ws;
    float*    h    = (float*)(ws + OFF_H);
    ushort_t* Ap   = (ushort_t*)(ws + OFF_APACK);
    float*    sqb  = (float*)(ws + OFF_SQ);
    int*      idxb = (int*)  (ws + OFF_IDX);
    double*   stats= (double*)(ws + OFF_STATS);
    float*    scsh = (float*)(ws + OFF_SCSH);
    float*    bcat = (float*)(ws + OFF_BCAT);
    float*    p0   = (float*)(ws + OFF_P0);
    float*    p1   = (float*)(ws + OFF_P1);
    float*    p2   = (float*)(ws + OFF_P2);
    float*    dmat = (float*)(ws + OFF_D);
    float*    t    = (float*)(ws + OFF_T);
    float*    uv   = (float*)(ws + OFF_UV);
    float*    y    = (float*)(ws + OFF_UV);
    ushort_t* Qw   = (ushort_t*)(ws + OFF_QW);
    float*    pmax = (float*)(ws + OFF_PMAX);

    auto bn_pre = [&](const float* src, const float* g, const float* b) {
        hipLaunchKernelGGL(bn_zero, dim3(1), dim3(512), 0, stream, stats);
        hipLaunchKernelGGL(bn_stats, dim3(256), dim3(256), 0, stream, src, stats);
        hipLaunchKernelGGL(bn_final, dim3(1), dim3(256), 0, stream, stats, g, b, scsh);
    };

    // h = x@Wf+bf (+pack), t = h@Wnn+bnn via MFMA
    hipLaunchKernelGGL(feat_pack, dim3(BN_), dim3(256), 0, stream, x, Wf, bfv, h, Ap);
    hipLaunchKernelGGL(pack_wT, dim3(H_), dim3(256), 0, stream, Wnn, Qw, H_);
    hipLaunchKernelGGL(mfma_gemm, dim3(2, 128), dim3(256), 0, stream,
                       Ap, Qw, bnn, t, KP_, H_, 0,
                       (const float*)nullptr, (const float*)nullptr, 0);

    for (int l = 0; l < L_; ++l) {
        const float* src1 = (l == 0) ? t : h;
        bn_pre(src1, g1 + l * H_, b1 + l * H_);
        hipLaunchKernelGGL(bn_apply_pack, dim3(BN_), dim3(256), 0, stream,
                           src1, scsh, Ap, sqb);
        // symmetric gram -> D (both triangles written, upper computed), XCD-pinned
        hipLaunchKernelGGL(gram_sym, dim3(1088), dim3(256), 0, stream,
                           Ap, sqb, dmat);
        hipLaunchKernelGGL(topk16, dim3(BN_ / 4), dim3(256), 0, stream, dmat, idxb);
        // fused u|v gemm (N=512)
        hipLaunchKernelGGL(pack_qcat, dim3(512), dim3(256), 0, stream,
                           We + (size_t)l * 2 * H_ * H_, be + (size_t)l * H_, Qw, bcat);
        hipLaunchKernelGGL(mfma_gemm, dim3(4, 128), dim3(256), 0, stream,
                           Ap, Qw, bcat, uv, KP_, 512, 0,
                           (const float*)nullptr, (const float*)nullptr, 0);
        hipLaunchKernelGGL(gather_max, dim3(BN_), dim3(256), 0, stream, uv, idxb, t);
        // BN2 + Wl with fused residual: h = h + alpha[l]*(xb@Wl + bl)
        bn_pre(t, g2 + l * H_, b2 + l * H_);
        hipLaunchKernelGGL(bn_apply_pack, dim3(BN_), dim3(256), 0, stream,
                           t, scsh, Ap, (float*)nullptr);
        hipLaunchKernelGGL(pack_wT, dim3(H_), dim3(256), 0, stream,
                           Wl + (size_t)l * H_ * H_, Qw, H_);
        hipLaunchKernelGGL(mfma_gemm, dim3(2, 128), dim3(256), 0, stream,
                           Ap, Qw, bl + (size_t)l * H_, h, KP_, H_, 2,
                           h, alpha, l);
    }

    // head
    bn_pre(h, gg, bgb);
    hipLaunchKernelGGL(bn_apply_pack, dim3(BN_), dim3(256), 0, stream,
                       h, scsh, Ap, (float*)nullptr);
    hipLaunchKernelGGL(pack_wT, dim3(G_), dim3(256), 0, stream, Wg, Qw, G_);
    hipLaunchKernelGGL(mfma_gemm, dim3(4, 128), dim3(256), 0, stream,
                       Ap, Qw, bg2, y, KP_, G_, 0,
                       (const float*)nullptr, (const float*)nullptr, 0);
    hipLaunchKernelGGL(maxpool1, dim3(8, 2, 16), dim3(256), 0, stream, y, pmax);
    hipLaunchKernelGGL(maxpool2, dim3(8, 2), dim3(256), 0, stream, pmax, p0);
    hipLaunchKernelGGL(head_gemm, dim3(8, 4), dim3(256), 0, stream, p0, Wm1, bm1, p1, G_, M0_, 1);
    hipLaunchKernelGGL(head_gemm, dim3(8, 2), dim3(256), 0, stream, p1, Wm2, bm2, p2, M0_, M1_, 1);
    hipLaunchKernelGGL(head_gemm, dim3(8, 2), dim3(256), 0, stream, p2, Wm3, bm3, outp, M1_, C_, 0);
}

// Round 9
// 1248.493 us; speedup vs baseline: 1.6759x; 1.2313x over previous
//
#include <hip/hip_runtime.h>
#include <cfloat>

#define B_  8
#define N_  2048
#define H_  256
#define L_  4
#define K_  16
#define G_  512
#define M0_ 256
#define M1_ 128
#define C_  128
#define BN_ 16384   // B_*N_
#define KP_ 768     // packed split-bf16 K (3*H_)

typedef unsigned short ushort_t;
typedef __attribute__((ext_vector_type(8))) short short8;
typedef __attribute__((ext_vector_type(4))) float f32x4;

// ---------------- workspace layout (bytes) ----------------
#define OFF_H     ((size_t)0)            // 16 MB  h (fp32, persistent)
#define OFF_APACK ((size_t)16777216)     // 25.2 MB  P-pack [hi,lo,hi] (Q read via seg remap)
#define OFF_SQ    ((size_t)67108864)     // 64 KB
#define OFF_IDX   ((size_t)67174400)     // 1 MB
#define OFF_STATS ((size_t)68222976)     // 4 KB (512 doubles)
#define OFF_SCSH  ((size_t)68227072)     // 2 KB
#define OFF_BCAT  ((size_t)68229120)     // 2 KB
#define OFF_P0    ((size_t)68231168)     // 16 KB
#define OFF_P1    ((size_t)68247552)
#define OFF_P2    ((size_t)68255744)
#define OFF_D     ((size_t)69206016)     // 134.2 MB dmat; overlays below (stream-ordered safe)
#define OFF_T     (OFF_D + (size_t)0)           // 16 MB (alive gather_max -> bn2; dmat dead)
#define OFF_UV    (OFF_D + (size_t)50331648)    // 33.5 MB (alive uv gemm -> gather); also y
#define OFF_QW    (OFF_D + (size_t)83886080)    // 0.79 MB weight packs
#define OFF_PMAX  (OFF_D + (size_t)84672512)    // 256 KB
#define WS_NEEDED ((size_t)203423744)

// ---------------- helpers ----------------
static __device__ __forceinline__ ushort_t f2bf(float f) {
    unsigned u = __float_as_uint(f);
    unsigned r = (u + 0x7fffu + ((u >> 16) & 1u)) >> 16;   // RNE
    return (ushort_t)r;
}
static __device__ __forceinline__ float bf2f(ushort_t h) {
    return __uint_as_float(((unsigned)h) << 16);
}
// P-pack layout per row: [hi(0:256), lo(256:512), hi(512:768)]
static __device__ __forceinline__ void pack3(float v, ushort_t* A, size_t base, int f) {
    ushort_t hi = f2bf(v);
    ushort_t lo = f2bf(v - bf2f(hi));
    A[base + f] = hi; A[base + H_ + f] = lo; A[base + 2 * H_ + f] = hi;
}

// ---------------- kernels ----------------

// h = x @ Wf + bf ; also pack h into Apack
__global__ void feat_pack(const float* __restrict__ x, const float* __restrict__ Wf,
                          const float* __restrict__ bfv, float* __restrict__ h,
                          ushort_t* __restrict__ Ap) {
    int pt = blockIdx.x;
    int f  = threadIdx.x;
    float x0 = x[pt * 3 + 0], x1 = x[pt * 3 + 1], x2 = x[pt * 3 + 2];
    float v = x0 * Wf[f] + x1 * Wf[H_ + f] + x2 * Wf[2 * H_ + f] + bfv[f];
    h[(size_t)pt * H_ + f] = v;
    pack3(v, Ap, (size_t)pt * KP_, f);
}

// W (256 x Nd) -> Qpack (Nd x 768) rows [hi,hi,lo] of W^T
__global__ void pack_wT(const float* __restrict__ W, ushort_t* __restrict__ Qp, int Nd) {
    int n = blockIdx.x, k = threadIdx.x;
    float w = W[(size_t)k * Nd + n];
    ushort_t hi = f2bf(w), lo = f2bf(w - bf2f(hi));
    size_t base = (size_t)n * KP_;
    Qp[base + k] = hi; Qp[base + H_ + k] = hi; Qp[base + 2 * H_ + k] = lo;
}

// Qcat for fused u|v gemm: rows 0..255 = (We_a - We_b)^T, rows 256..511 = We_b^T
__global__ void pack_qcat(const float* __restrict__ We_l, const float* __restrict__ be_l,
                          ushort_t* __restrict__ Qp, float* __restrict__ bcat) {
    int n = blockIdx.x, k = threadIdx.x;
    float w;
    if (n < H_) w = We_l[(size_t)k * H_ + n] - We_l[(size_t)H_ * H_ + (size_t)k * H_ + n];
    else        w = We_l[(size_t)H_ * H_ + (size_t)k * H_ + (n - H_)];
    ushort_t hi = f2bf(w), lo = f2bf(w - bf2f(hi));
    size_t base = (size_t)n * KP_;
    Qp[base + k] = hi; Qp[base + H_ + k] = hi; Qp[base + 2 * H_ + k] = lo;
    if (k == 0) bcat[n] = (n < H_) ? be_l[n] : 0.f;
}

// ---- split-bf16 MFMA GEMM: out = P (M x K) . Q^T (N x K) ----
// mode 0: out[r][c] = acc + aux[c]
// mode 2: out[r][c] = resid[r][c] + alphap[aidx]*(acc+aux[c])
__global__ __launch_bounds__(256) void mfma_gemm(
    const ushort_t* __restrict__ P, const ushort_t* __restrict__ Q,
    const float* __restrict__ aux, float* __restrict__ out,
    int Kd, int ldOut, int mode, const float* __restrict__ resid,
    const float* __restrict__ alphap, int aidx) {
    __shared__ __align__(16) ushort_t As[128 * 32];
    __shared__ __align__(16) ushort_t Bs[128 * 32];
    int i0 = blockIdx.y * 128, j0 = blockIdx.x * 128;
    int tid = threadIdx.x;
    int lane = tid & 63, wave = tid >> 6;
    int wm = wave & 1, wn = wave >> 1;
    int m16 = lane & 15, kq = (lane >> 4) * 8;

    f32x4 acc[4][4];
    f32x4 zero = {0.f, 0.f, 0.f, 0.f};
#pragma unroll
    for (int i = 0; i < 4; ++i)
#pragma unroll
        for (int j = 0; j < 4; ++j) acc[i][j] = zero;

    int srow = tid >> 2;
    int skc  = (tid & 3) * 8;

    for (int k0 = 0; k0 < Kd; k0 += 32) {
#pragma unroll
        for (int s = 0; s < 2; ++s) {
            int row = srow + s * 64;
            const ushort_t* gpA = P + (size_t)(i0 + row) * Kd + k0 + skc;
            const ushort_t* gpB = Q + (size_t)(j0 + row) * Kd + k0 + skc;
            __builtin_amdgcn_global_load_lds(
                (const __attribute__((address_space(1))) void*)gpA,
                (__attribute__((address_space(3))) void*)(As + (size_t)(wave * 64 + s * 256) * 8),
                16, 0, 0);
            __builtin_amdgcn_global_load_lds(
                (const __attribute__((address_space(1))) void*)gpB,
                (__attribute__((address_space(3))) void*)(Bs + (size_t)(wave * 64 + s * 256) * 8),
                16, 0, 0);
        }
        __syncthreads();
        short8 af[4], bfr[4];
#pragma unroll
        for (int fi = 0; fi < 4; ++fi)
            af[fi] = *(const short8*)(As + (wm * 64 + fi * 16 + m16) * 32 + kq);
#pragma unroll
        for (int fj = 0; fj < 4; ++fj)
            bfr[fj] = *(const short8*)(Bs + (wn * 64 + fj * 16 + m16) * 32 + kq);
#pragma unroll
        for (int fi = 0; fi < 4; ++fi)
#pragma unroll
            for (int fj = 0; fj < 4; ++fj)
                acc[fi][fj] = __builtin_amdgcn_mfma_f32_16x16x32_bf16(
                    af[fi], bfr[fj], acc[fi][fj], 0, 0, 0);
        __syncthreads();
    }
    float alpha = (mode == 2) ? alphap[aidx] : 0.f;
    int rbase = i0 + wm * 64 + (lane >> 4) * 4;
    int cbase = j0 + wn * 64 + m16;
#pragma unroll
    for (int fi = 0; fi < 4; ++fi) {
#pragma unroll
        for (int fj = 0; fj < 4; ++fj) {
            int c = cbase + fj * 16;
            float a = aux[c];
#pragma unroll
            for (int r = 0; r < 4; ++r) {
                int gr = rbase + fi * 16 + r;
                size_t oidx = (size_t)gr * ldOut + c;
                float val;
                if (mode == 2) val = resid[oidx] + alpha * (acc[fi][fj][r] + a);
                else           val = acc[fi][fj][r] + a;
                out[oidx] = val;
            }
        }
    }
}

// ---- symmetric gram: D[i][j] = sq[j] - 2 <x_i, x_j>, upper-tri tile pairs only ----
// 1-D grid 1088: z = blk&7 (XCD pin), p = blk>>3 enumerates bi<=bj tile pairs.
// B-side reads P-pack with segment remap (0,2,1). Direct NT stores from registers.
__global__ __launch_bounds__(256) void gram_sym(const ushort_t* __restrict__ Ap,
                                                const float* __restrict__ sqb,
                                                float* __restrict__ D) {
    __shared__ __align__(16) ushort_t As[128 * 32];
    __shared__ __align__(16) ushort_t Bs[128 * 32];
    int blk = blockIdx.x;
    int z = blk & 7;
    int p = blk >> 3;
    int bi = 0, rem = p;
    while (rem >= 16 - bi) { rem -= 16 - bi; ++bi; }
    int bj = bi + rem;
    const ushort_t* Pz = Ap + (size_t)z * N_ * KP_;
    const float* sqz = sqb + (size_t)z * N_;
    float* Dz = D + (size_t)z * N_ * N_;
    int i0 = bi * 128, j0 = bj * 128;

    int tid = threadIdx.x;
    int lane = tid & 63, wave = tid >> 6;
    int wm = wave & 1, wn = wave >> 1;
    int m16 = lane & 15, q4 = lane >> 4;
    int kq = q4 * 8;

    f32x4 acc[4][4];
    f32x4 zero = {0.f, 0.f, 0.f, 0.f};
#pragma unroll
    for (int i = 0; i < 4; ++i)
#pragma unroll
        for (int j = 0; j < 4; ++j) acc[i][j] = zero;

    int srow = tid >> 2;
    int skc  = (tid & 3) * 8;

    for (int k0 = 0; k0 < KP_; k0 += 32) {
        // Q segment remap: seg0->seg0(hi), seg1->seg2(hi), seg2->seg1(lo)
        int kb = (k0 < 256) ? k0 : ((k0 < 512) ? k0 + 256 : k0 - 256);
#pragma unroll
        for (int s = 0; s < 2; ++s) {
            int row = srow + s * 64;
            const ushort_t* gpA = Pz + (size_t)(i0 + row) * KP_ + k0 + skc;
            const ushort_t* gpB = Pz + (size_t)(j0 + row) * KP_ + kb + skc;
            __builtin_amdgcn_global_load_lds(
                (const __attribute__((address_space(1))) void*)gpA,
                (__attribute__((address_space(3))) void*)(As + (size_t)(wave * 64 + s * 256) * 8),
                16, 0, 0);
            __builtin_amdgcn_global_load_lds(
                (const __attribute__((address_space(1))) void*)gpB,
                (__attribute__((address_space(3))) void*)(Bs + (size_t)(wave * 64 + s * 256) * 8),
                16, 0, 0);
        }
        __syncthreads();
        short8 af[4], bfr[4];
#pragma unroll
        for (int fi = 0; fi < 4; ++fi)
            af[fi] = *(const short8*)(As + (wm * 64 + fi * 16 + m16) * 32 + kq);
#pragma unroll
        for (int fj = 0; fj < 4; ++fj)
            bfr[fj] = *(const short8*)(Bs + (wn * 64 + fj * 16 + m16) * 32 + kq);
#pragma unroll
        for (int fi = 0; fi < 4; ++fi)
#pragma unroll
            for (int fj = 0; fj < 4; ++fj)
                acc[fi][fj] = __builtin_amdgcn_mfma_f32_16x16x32_bf16(
                    af[fi], bfr[fj], acc[fi][fj], 0, 0, 0);
        __syncthreads();
    }
    int rbase = i0 + wm * 64 + q4 * 4;
    int cbase = j0 + wn * 64 + m16;
#pragma unroll
    for (int fi = 0; fi < 4; ++fi) {
        int gr0 = rbase + fi * 16;
        float4 s4 = *(const float4*)(sqz + gr0);   // sq of this lane's 4 rows
        float sr[4] = {s4.x, s4.y, s4.z, s4.w};
#pragma unroll
        for (int fj = 0; fj < 4; ++fj) {
            int c = cbase + fj * 16;
            float sc = sqz[c];
#pragma unroll
            for (int r = 0; r < 4; ++r)
                __builtin_nontemporal_store(sc - 2.f * acc[fi][fj][r],
                                            Dz + (size_t)(gr0 + r) * N_ + c);
            if (bi != bj) {   // transposed tile: D[c][gr0..gr0+3], contiguous 16B
                f32x4 o;
                o[0] = sr[0] - 2.f * acc[fi][fj][0];
                o[1] = sr[1] - 2.f * acc[fi][fj][1];
                o[2] = sr[2] - 2.f * acc[fi][fj][2];
                o[3] = sr[3] - 2.f * acc[fi][fj][3];
                __builtin_nontemporal_store(o, (f32x4*)(Dz + (size_t)c * N_ + gr0));
            }
        }
    }
}

// ---- threshold top-16 smallest per row (exact, lex (value,col) tie-break) ----
// wave-per-row. T = 16th-smallest of the 64 lane-minima (valid bound: 16 distinct
// lanes each hold one element <= their min). Candidates <= T (E[count]~16-40) go
// through one LDS atomic each; 16 rounds of register u64 butterfly extraction.
__global__ __launch_bounds__(256) void topk16(const float* __restrict__ D,
                                              int* __restrict__ idxb) {
    __shared__ unsigned long long cand[4][256];
    __shared__ int cnt[4];
    int w = threadIdx.x >> 6, lane = threadIdx.x & 63;
    int row = blockIdx.x * 4 + w;
    const float* dp = D + (size_t)row * N_;
    unsigned sk[32];
#pragma unroll
    for (int t = 0; t < 8; ++t) {
        f32x4 v4 = __builtin_nontemporal_load((const f32x4*)(dp + t * 256 + lane * 4));
#pragma unroll
        for (int j = 0; j < 4; ++j) {
            unsigned u = __float_as_uint(v4[j]);
            sk[t * 4 + j] = (u & 0x80000000u) ? ~u : (u | 0x80000000u);
        }
    }
    if (lane == 0) cnt[w] = 0;
    // per-lane min
    unsigned vm = sk[0];
#pragma unroll
    for (int i = 1; i < 32; ++i) vm = min(vm, sk[i]);
    // bitonic sort of 64 lane-minima (ascending across lanes), shuffle-only
#pragma unroll
    for (int k = 2; k <= 64; k <<= 1) {
#pragma unroll
        for (int j = k >> 1; j > 0; j >>= 1) {
            unsigned pv = __shfl_xor(vm, j);
            bool up = ((lane & k) == 0);
            bool lower = ((lane & j) == 0);
            unsigned mn = min(vm, pv), mx = max(vm, pv);
            vm = (lower == up) ? mn : mx;
        }
    }
    unsigned T = __shfl(vm, 15);   // 16th smallest lane-min >= 16th order statistic
    __syncthreads();
    // emit candidates <= T
#pragma unroll
    for (int i = 0; i < 32; ++i) {
        if (sk[i] <= T) {
            unsigned col = (unsigned)((i >> 2) * 256 + lane * 4 + (i & 3));
            int s = atomicAdd(&cnt[w], 1);
            if (s < 256) cand[w][s] = ((unsigned long long)sk[i] << 32) | col;
        }
    }
    __syncthreads();
    int cn = cnt[w];
    if (cn <= 64) {
        unsigned long long mykey = (lane < cn) ? cand[w][lane] : ~0ull;
        for (int it = 0; it < 16; ++it) {
            unsigned long long best = mykey;
#pragma unroll
            for (int off = 32; off; off >>= 1) {
                unsigned long long o = __shfl_xor(best, off);
                if (o < best) best = o;
            }
            if (mykey == best) mykey = ~0ull;
            if (lane == 0) idxb[row * 16 + it] = (int)(unsigned)(best & 0xffffffffu);
        }
    } else if (cn <= 256) {
        for (int it = 0; it < 16; ++it) {
            unsigned long long best = ~0ull;
            for (int i = lane; i < cn; i += 64) {
                unsigned long long c = cand[w][i];
                if (c < best) best = c;
            }
#pragma unroll
            for (int off = 32; off; off >>= 1) {
                unsigned long long o = __shfl_xor(best, off);
                if (o < best) best = o;
            }
            for (int i = lane; i < cn; i += 64)
                if (cand[w][i] == best) cand[w][i] = ~0ull;
            if (lane == 0) idxb[row * 16 + it] = (int)(unsigned)(best & 0xffffffffu);
        }
    } else {
        // pathological tie storm: full iterative selection, exact
        unsigned mask = 0;
        for (int it = 0; it < 16; ++it) {
            unsigned long long key = ~0ull;
#pragma unroll
            for (int i = 0; i < 32; ++i) {
                if (!((mask >> i) & 1u)) {
                    unsigned long long k2 = ((unsigned long long)sk[i] << 32) |
                        (unsigned)((i >> 2) * 256 + lane * 4 + (i & 3));
                    if (k2 < key) key = k2;
                }
            }
#pragma unroll
            for (int off = 32; off; off >>= 1) {
                unsigned long long o = __shfl_xor(key, off);
                if (o < key) key = o;
            }
            unsigned jc = (unsigned)(key & 0xffffffffu);
            int li = ((jc & 255) >> 2);            // owner lane = (col%256)/4
            int ii = ((jc >> 8) << 2) | (jc & 3);  // sk index = (col/256)*4 + col%4
            if (lane == li) mask |= 1u << ii;
            if (lane == 0) idxb[row * 16 + it] = (int)jc;
        }
    }
}

// t[b,i,h] = uv[row][h] + max_k uv[(b,idx_k)][256+h]
__global__ void gather_max(const float* __restrict__ uv, const int* __restrict__ idxb,
                           float* __restrict__ outp) {
    int row = blockIdx.x;
    int b = row >> 11;
    int h = threadIdx.x;
    const int* ip = idxb + row * 16;
    float m = -FLT_MAX;
#pragma unroll
    for (int k = 0; k < 16; ++k) {
        int j = ip[k];
        m = fmaxf(m, uv[((size_t)((b << 11) + j)) * 512 + 256 + h]);
    }
    outp[(size_t)row * H_ + h] = uv[(size_t)row * 512 + h] + m;
}

// ---- batchnorm over (B,N) per feature ----
__global__ void bn_zero(double* s) { s[threadIdx.x] = 0.0; }

__global__ void bn_stats(const float* __restrict__ X, double* __restrict__ sums) {
    int f = threadIdx.x;
    int r0 = blockIdx.x * 64;
    double s = 0.0, s2 = 0.0;
    for (int r = 0; r < 64; ++r) {
        float v = X[(size_t)(r0 + r) * H_ + f];
        s += v; s2 += (double)v * v;
    }
    atomicAdd(&sums[f], s);
    atomicAdd(&sums[H_ + f], s2);
}

__global__ void bn_final(const double* __restrict__ sums, const float* __restrict__ g,
                         const float* __restrict__ b, float* __restrict__ scsh) {
    int f = threadIdx.x;
    double m  = sums[f] / (double)BN_;
    double var = sums[H_ + f] / (double)BN_ - m * m;
    double inv = 1.0 / sqrt(var + 1e-5);
    float sc = g[f] * (float)inv;
    scsh[f] = sc;
    scsh[H_ + f] = b[f] - (float)m * sc;
}

// BN+ReLU fused with split-bf16 packing and (optional) row sqnorm reduce.
__global__ void bn_apply_pack(const float* __restrict__ X, const float* __restrict__ scsh,
                              ushort_t* __restrict__ Ap, float* __restrict__ sq) {
    int row = blockIdx.x, f = threadIdx.x;
    float v = X[(size_t)row * H_ + f] * scsh[f] + scsh[H_ + f];
    v = fmaxf(v, 0.f);
    pack3(v, Ap, (size_t)row * KP_, f);
    if (sq) {
        float s = v * v;
#pragma unroll
        for (int off = 32; off; off >>= 1) s += __shfl_down(s, off);
        __shared__ float red[4];
        if ((f & 63) == 0) red[f >> 6] = s;
        __syncthreads();
        if (f == 0) sq[row] = red[0] + red[1] + red[2] + red[3];
    }
}

__global__ void maxpool1(const float* __restrict__ y, float* __restrict__ pmax) {
    int b = blockIdx.x, gc = blockIdx.y, nc = blockIdx.z;
    int g = gc * 256 + threadIdx.x;
    const float* yb = y + ((size_t)b * N_ + (size_t)nc * 128) * G_;
    float m = -FLT_MAX;
    for (int n = 0; n < 128; ++n) m = fmaxf(m, yb[(size_t)n * G_ + g]);
    pmax[((size_t)(b * 16 + nc)) * G_ + g] = m;
}

__global__ void maxpool2(const float* __restrict__ pmax, float* __restrict__ p) {
    int b = blockIdx.x;
    int g = blockIdx.y * 256 + threadIdx.x;
    float m = -FLT_MAX;
    for (int c = 0; c < 16; ++c) m = fmaxf(m, pmax[((size_t)(b * 16 + c)) * G_ + g]);
    p[(size_t)b * G_ + g] = m;
}

// parallel split-K head gemm: grid(M, Nd/64), 256 thr = 64 cols x 4 k-slices
__global__ __launch_bounds__(256) void head_gemm(const float* __restrict__ A,
                                                 const float* __restrict__ W,
                                                 const float* __restrict__ bias,
                                                 float* __restrict__ Cc,
                                                 int Kd, int Nd, int relu) {
    int m = blockIdx.x;
    int c0 = blockIdx.y * 64;
    int cl = threadIdx.x & 63;
    int ks = threadIdx.x >> 6;
    int kper = Kd >> 2;
    const float* Ap = A + (size_t)m * Kd + (size_t)ks * kper;
    const float* Wp = W + (size_t)ks * kper * Nd + c0 + cl;
    float acc = 0.f;
    for (int k = 0; k < kper; k += 8) {
#pragma unroll
        for (int u2 = 0; u2 < 8; ++u2)
            acc += Ap[k + u2] * Wp[(size_t)(k + u2) * Nd];
    }
    __shared__ float red[4][64];
    red[ks][cl] = acc;
    __syncthreads();
    if (ks == 0) {
        float s = red[0][cl] + red[1][cl] + red[2][cl] + red[3][cl] + bias[c0 + cl];
        if (relu) s = fmaxf(s, 0.f);
        Cc[(size_t)m * Nd + c0 + cl] = s;
    }
}

// ---------------- launch ----------------
extern "C" void kernel_launch(void* const* d_in, const int* in_sizes, int n_in,
                              void* d_out, int out_size, void* d_ws, size_t ws_size,
                              hipStream_t stream) {
    (void)in_sizes; (void)n_in; (void)out_size;
    if (ws_size < WS_NEEDED) return;

    const float* x    = (const float*)d_in[0];
    const float* Wf   = (const float*)d_in[2];
    const float* bfv  = (const float*)d_in[3];
    const float* Wnn  = (const float*)d_in[4];
    const float* bnn  = (const float*)d_in[5];
    const float* g1   = (const float*)d_in[6];
    const float* b1   = (const float*)d_in[7];
    const float* We   = (const float*)d_in[8];
    const float* be   = (const float*)d_in[9];
    const float* g2   = (const float*)d_in[10];
    const float* b2   = (const float*)d_in[11];
    const float* Wl   = (const float*)d_in[12];
    const float* bl   = (const float*)d_in[13];
    const float* alpha= (const float*)d_in[14];
    const float* gg   = (const float*)d_in[15];
    const float* bgb  = (const float*)d_in[16];
    const float* Wg   = (const float*)d_in[17];
    const float* bg2  = (const float*)d_in[18];
    const float* Wm1  = (const float*)d_in[19];
    const float* bm1  = (const float*)d_in[20];
    const float* Wm2  = (const float*)d_in[21];
    const float* bm2  = (const float*)d_in[22];
    const float* Wm3  = (const float*)d_in[23];
    const float* bm3  = (const float*)d_in[24];
    float* outp = (float*)d_out;

    char* ws = (char*)d_ws;
    float*    h    = (float*)(ws + OFF_H);
    ushort_t* Ap   = (ushort_t*)(ws + OFF_APACK);
    float*    sqb  = (float*)(ws + OFF_SQ);
    int*      idxb = (int*)  (ws + OFF_IDX);
    double*   stats= (double*)(ws + OFF_STATS);
    float*    scsh = (float*)(ws + OFF_SCSH);
    float*    bcat = (float*)(ws + OFF_BCAT);
    float*    p0   = (float*)(ws + OFF_P0);
    float*    p1   = (float*)(ws + OFF_P1);
    float*    p2   = (float*)(ws + OFF_P2);
    float*    dmat = (float*)(ws + OFF_D);
    float*    t    = (float*)(ws + OFF_T);
    float*    uv   = (float*)(ws + OFF_UV);
    float*    y    = (float*)(ws + OFF_UV);
    ushort_t* Qw   = (ushort_t*)(ws + OFF_QW);
    float*    pmax = (float*)(ws + OFF_PMAX);

    auto bn_pre = [&](const float* src, const float* g, const float* b) {
        hipLaunchKernelGGL(bn_zero, dim3(1), dim3(512), 0, stream, stats);
        hipLaunchKernelGGL(bn_stats, dim3(256), dim3(256), 0, stream, src, stats);
        hipLaunchKernelGGL(bn_final, dim3(1), dim3(256), 0, stream, stats, g, b, scsh);
    };

    // h = x@Wf+bf (+pack), t = h@Wnn+bnn via MFMA
    hipLaunchKernelGGL(feat_pack, dim3(BN_), dim3(256), 0, stream, x, Wf, bfv, h, Ap);
    hipLaunchKernelGGL(pack_wT, dim3(H_), dim3(256), 0, stream, Wnn, Qw, H_);
    hipLaunchKernelGGL(mfma_gemm, dim3(2, 128), dim3(256), 0, stream,
                       Ap, Qw, bnn, t, KP_, H_, 0,
                       (const float*)nullptr, (const float*)nullptr, 0);

    for (int l = 0; l < L_; ++l) {
        const float* src1 = (l == 0) ? t : h;
        bn_pre(src1, g1 + l * H_, b1 + l * H_);
        hipLaunchKernelGGL(bn_apply_pack, dim3(BN_), dim3(256), 0, stream,
                           src1, scsh, Ap, sqb);
        // symmetric gram -> D (both triangles written, upper computed), XCD-pinned
        hipLaunchKernelGGL(gram_sym, dim3(1088), dim3(256), 0, stream,
                           Ap, sqb, dmat);
        hipLaunchKernelGGL(topk16, dim3(BN_ / 4), dim3(256), 0, stream, dmat, idxb);
        // fused u|v gemm (N=512)
        hipLaunchKernelGGL(pack_qcat, dim3(512), dim3(256), 0, stream,
                           We + (size_t)l * 2 * H_ * H_, be + (size_t)l * H_, Qw, bcat);
        hipLaunchKernelGGL(mfma_gemm, dim3(4, 128), dim3(256), 0, stream,
                           Ap, Qw, bcat, uv, KP_, 512, 0,
                           (const float*)nullptr, (const float*)nullptr, 0);
        hipLaunchKernelGGL(gather_max, dim3(BN_), dim3(256), 0, stream, uv, idxb, t);
        // BN2 + Wl with fused residual: h = h + alpha[l]*(xb@Wl + bl)
        bn_pre(t, g2 + l * H_, b2 + l * H_);
        hipLaunchKernelGGL(bn_apply_pack, dim3(BN_), dim3(256), 0, stream,
                           t, scsh, Ap, (float*)nullptr);
        hipLaunchKernelGGL(pack_wT, dim3(H_), dim3(256), 0, stream,
                           Wl + (size_t)l * H_ * H_, Qw, H_);
        hipLaunchKernelGGL(mfma_gemm, dim3(2, 128), dim3(256), 0, stream,
                           Ap, Qw, bl + (size_t)l * H_, h, KP_, H_, 2,
                           h, alpha, l);
    }

    // head
    bn_pre(h, gg, bgb);
    hipLaunchKernelGGL(bn_apply_pack, dim3(BN_), dim3(256), 0, stream,
                       h, scsh, Ap, (float*)nullptr);
    hipLaunchKernelGGL(pack_wT, dim3(G_), dim3(256), 0, stream, Wg, Qw, G_);
    hipLaunchKernelGGL(mfma_gemm, dim3(4, 128), dim3(256), 0, stream,
                       Ap, Qw, bg2, y, KP_, G_, 0,
                       (const float*)nullptr, (const float*)nullptr, 0);
    hipLaunchKernelGGL(maxpool1, dim3(8, 2, 16), dim3(256), 0, stream, y, pmax);
    hipLaunchKernelGGL(maxpool2, dim3(8, 2), dim3(256), 0, stream, pmax, p0);
    hipLaunchKernelGGL(head_gemm, dim3(8, 4), dim3(256), 0, stream, p0, Wm1, bm1, p1, G_, M0_, 1);
    hipLaunchKernelGGL(head_gemm, dim3(8, 2), dim3(256), 0, stream, p1, Wm2, bm2, p2, M0_, M1_, 1);
    hipLaunchKernelGGL(head_gemm, dim3(8, 2), dim3(256), 0, stream, p2, Wm3, bm3, outp, M1_, C_, 0);
}